// Round 13
// baseline (792.312 us; speedup 1.0000x reference)
//
#include <hip/hip_runtime.h>
#include <stdint.h>

#define NNODES 50000
#define NEDGES 800000
#define NGRAPH 100
#define NPAIR (NEDGES / 32)    // 25000 chunk-pairs (2 x 16 edges)
#define NWAVES 4096            // 256 blocks x 16 waves

typedef _Float16 f16;
typedef __attribute__((ext_vector_type(8))) _Float16 half8;
typedef __attribute__((ext_vector_type(4))) _Float16 half4;
typedef __attribute__((ext_vector_type(4))) float floatx4;

// stage 128x128 fp32 row-major W[k][n] -> LDS WT[n][136 pad] fp16, float4 loads
__device__ __forceinline__ void stage_WT(const float* __restrict__ W, f16* WT,
                                         int tid, int nthr) {
    for (int idx = tid; idx < 128 * 32; idx += nthr) {
        int k = idx >> 5, n4 = (idx & 31) * 4;
        floatx4 v = *(const floatx4*)(W + k * 128 + n4);
        WT[(n4 + 0) * 136 + k] = (f16)v[0];
        WT[(n4 + 1) * 136 + k] = (f16)v[1];
        WT[(n4 + 2) * 136 + k] = (f16)v[2];
        WT[(n4 + 3) * 136 + k] = (f16)v[3];
    }
}

__device__ __forceinline__ float fast_tanh(float x) {
    x = fminf(fmaxf(x, -15.0f), 15.0f);
    float e2 = __expf(2.0f * x);
    return (e2 - 1.0f) * __builtin_amdgcn_rcpf(e2 + 1.0f);
}

// transposed-m: column c owns f16 elements [c*16, c*16+16); row groups of 4
// rotated by (c>>2) to spread banks. Bijective per column -> collision-free.
__device__ __forceinline__ int mtAddr(int c, int rgroup) {
    return c * 16 + ((((c >> 2) + rgroup) & 3) << 2);
}

__global__ void init_k(float* out, int osz, int* cnt) {
    int i = blockIdx.x * 256 + threadIdx.x;
    if (i < osz) out[i] = 0.0f;
    if (i < NNODES) cnt[i] = 0;
}

__global__ void hist_k(const int* __restrict__ dst, int* __restrict__ cnt) {
    int e = blockIdx.x * 256 + threadIdx.x;
    if (e < NEDGES) atomicAdd(&cnt[dst[e]], 1);
}

__global__ __launch_bounds__(1024) void scan1_k(const int* __restrict__ cnt,
                                                int* __restrict__ rowStart,
                                                int* __restrict__ blockSum) {
    __shared__ int buf[1024];
    int tid = threadIdx.x;
    int i = blockIdx.x * 1024 + tid;
    int v = (i < NNODES) ? cnt[i] : 0;
    buf[tid] = v;
    __syncthreads();
    for (int off = 1; off < 1024; off <<= 1) {
        int t = (tid >= off) ? buf[tid - off] : 0;
        __syncthreads();
        buf[tid] += t;
        __syncthreads();
    }
    if (i < NNODES) rowStart[i] = buf[tid] - v;
    if (tid == 1023) blockSum[blockIdx.x] = buf[1023];
}

__global__ void scan2_k(int* __restrict__ blockSum, int nb) {
    if (threadIdx.x == 0) {
        int run = 0;
        for (int b = 0; b < nb; ++b) { int s = blockSum[b]; blockSum[b] = run; run += s; }
    }
}

__global__ __launch_bounds__(1024) void scan3_k(int* __restrict__ rowStart,
                                                const int* __restrict__ blockSum,
                                                int* __restrict__ cnt) {
    int i = blockIdx.x * 1024 + threadIdx.x;
    if (i < NNODES) { rowStart[i] += blockSum[blockIdx.x]; cnt[i] = 0; }
    if (i == 0) rowStart[NNODES] = NEDGES;
}

__global__ void scatter_k(const int* __restrict__ src, const int* __restrict__ et,
                          const int* __restrict__ dst, const float* __restrict__ dist,
                          const int* __restrict__ rowStart, int* __restrict__ cnt,
                          uint4* __restrict__ packE) {
    int e = blockIdx.x * 256 + threadIdx.x;
    if (e >= NEDGES) return;
    int d = dst[e];
    int pos = rowStart[d] + atomicAdd(&cnt[d], 1);
    uint4 pk;
    pk.x = (unsigned)src[e];
    pk.y = (unsigned)et[e];
    pk.z = (unsigned)d;
    pk.w = __float_as_uint(dist[e]);
    packE[pos] = pk;
}

__global__ void gather_h(const int* __restrict__ nt, const float* __restrict__ emb,
                         float* __restrict__ h) {
    int i = blockIdx.x * 256 + threadIdx.x;
    int row = i >> 5, c4 = (i & 31) * 4;
    if (row < NNODES)
        *(floatx4*)(h + row * 128 + c4) = *(const floatx4*)(emb + nt[row] * 128 + c4);
}

// MODE 0: relu(X@W1+b1)@W2+b2 -> Out f16   MODE 2: X@W1+b1 -> Out f16
// Operand-swapped MFMAs -> feature-contiguous C-layout, all LDS b64/b128.
template <int MODE>
__global__ __launch_bounds__(1024, 4) void mlp_kernel(
        const float* __restrict__ X, int M,
        const float* __restrict__ W1, const float* __restrict__ b1,
        const float* __restrict__ W2, const float* __restrict__ b2,
        f16* __restrict__ Out) {
    __shared__ f16 W1T[128 * 136];
    __shared__ f16 W2T[(MODE == 0) ? 128 * 136 : 8];
    __shared__ f16 xBuf[256 * 136];
    __shared__ float bias1[128];
    __shared__ float bias2[128];
    int tid = threadIdx.x;

    stage_WT(W1, W1T, tid, 1024);
    if (MODE == 0) stage_WT(W2, W2T, tid, 1024);
    if (tid < 128) { bias1[tid] = b1[tid]; bias2[tid] = (MODE == 0) ? b2[tid] : 0.0f; }

    int r0 = blockIdx.x * 256;
    for (int it = 0; it < 8; ++it) {
        int row = it * 32 + (tid >> 5);
        int c4 = (tid & 31) * 4;
        int gr = r0 + row;
        floatx4 x = {0.0f, 0.0f, 0.0f, 0.0f};
        if (gr < M) x = *(const floatx4*)(X + (size_t)gr * 128 + c4);
        half4 xh;
        xh[0] = (f16)x[0]; xh[1] = (f16)x[1]; xh[2] = (f16)x[2]; xh[3] = (f16)x[3];
        *(half4*)(xBuf + row * 136 + c4) = xh;
    }
    __syncthreads();

    int lane = tid & 63, wv = tid >> 6;
    int R = wv * 16;
    int n16 = lane & 15, q = lane >> 4;
    int gr = r0 + R + n16;

    half8 a[4];
    #pragma unroll
    for (int kk = 0; kk < 4; ++kk)
        a[kk] = *(const half8*)(xBuf + (R + n16) * 136 + kk * 32 + q * 8);

    #pragma unroll
    for (int f = 0; f < 8; ++f) {
        floatx4 acc = *(const floatx4*)(bias1 + f * 16 + q * 4);
        #pragma unroll
        for (int kk = 0; kk < 4; ++kk) {
            half8 aw = *(const half8*)(W1T + (f * 16 + n16) * 136 + kk * 32 + q * 8);
            acc = __builtin_amdgcn_mfma_f32_16x16x32_f16(aw, a[kk], acc, 0, 0, 0);
        }
        if (MODE == 0) {
            half4 y;
            #pragma unroll
            for (int i = 0; i < 4; ++i) y[i] = (f16)fmaxf(acc[i], 0.0f);
            *(half4*)(xBuf + (R + n16) * 136 + f * 16 + q * 4) = y;
        } else {
            half4 o;
            #pragma unroll
            for (int i = 0; i < 4; ++i) o[i] = (f16)acc[i];
            if (gr < M) *(half4*)(Out + (size_t)gr * 128 + f * 16 + q * 4) = o;
        }
    }

    if (MODE == 0) {
        #pragma unroll
        for (int kk = 0; kk < 4; ++kk)
            a[kk] = *(const half8*)(xBuf + (R + n16) * 136 + kk * 32 + q * 8);
        #pragma unroll
        for (int f = 0; f < 8; ++f) {
            floatx4 acc = *(const floatx4*)(bias2 + f * 16 + q * 4);
            #pragma unroll
            for (int kk = 0; kk < 4; ++kk) {
                half8 aw = *(const half8*)(W2T + (f * 16 + n16) * 136 + kk * 32 + q * 8);
                acc = __builtin_amdgcn_mfma_f32_16x16x32_f16(aw, a[kk], acc, 0, 0, 0);
            }
            half4 o;
            #pragma unroll
            for (int i = 0; i < 4; ++i) o[i] = (f16)acc[i];
            if (gr < M) *(half4*)(Out + (size_t)gr * 128 + f * 16 + q * 4) = o;
        }
    }
}

// ---------------------------------------------------------------------------
// Barrier-free edge kernel, WcT-SHARED PAIR version. 16 waves/block,
// 1 block/CU, wave-local. Chunk0 runs fully (T0->B0->C0->a2e0, R11 schedule),
// then chunk1 (T1->B1->C1->a2e1), then ONE shared E pass where each WcT
// fragment read feeds two MFMAs. Cross-chunk live state is ONLY a2e0
// (16 regs) -- R12's 80-reg parking (W2T sharing too) spilled to scratch
// (FETCH 80->193 MB). Memory order per pair = T0,P0,T1,P1 with
// sched_barrier(0) fences = R11's proven 16-rows-in-flight profile.
// ---------------------------------------------------------------------------
__global__ __launch_bounds__(1024, 4) void edge_kernel(
        const uint4* __restrict__ packE,
        const f16* __restrict__ P, const f16* __restrict__ T,
        const float* __restrict__ We1,
        const float* __restrict__ We2, const float* __restrict__ be2,
        const float* __restrict__ Wc,  const float* __restrict__ bc,
        float* __restrict__ h) {
    __shared__ f16 W2T[128 * 136];       // 34816 B
    __shared__ f16 WcT[128 * 136];       // 34816 B
    __shared__ f16 W1rT[128 * 40];       // 10240 B
    __shared__ f16 Uall[16 * 2176];      // 69632 B : per-wave 16x136 time-shared
    __shared__ float sbe2[128], sbc[128];
    __shared__ int dstW[16][32];         // 2048 B
    // total ~152.5 KB -> 1 block/CU, 16 waves

    int tid = threadIdx.x;
    stage_WT(We2, W2T, tid, 1024);
    stage_WT(Wc,  WcT, tid, 1024);
    for (int idx = tid; idx < 128 * 32; idx += 1024) {
        int n = idx >> 5, kr = idx & 31;
        W1rT[n * 40 + kr] = (kr < 30) ? (f16)We1[(128 + kr) * 128 + n] : (f16)0.0f;
    }
    if (tid < 128) { sbe2[tid] = be2[tid]; sbc[tid] = bc[tid]; }
    __syncthreads();    // weights ready; the ONLY block barrier

    int lane = tid & 63, wv = tid >> 6;
    f16* U = Uall + wv * 2176;
    int* dW = dstW[wv];
    int n16 = lane & 15, q = lane >> 4;
    const float invgap = 29.0f / 10.0f;
    int colA = lane, colB = lane + 64;
    int tsub = lane & 3, trow = lane >> 2;

    float sbcv[8];
    #pragma unroll
    for (int f = 0; f < 8; ++f) sbcv[f] = sbc[f * 16 + n16];

    float carry0 = 0.0f, carry1 = 0.0f;
    int prev = -1;

    auto segreduce = [&](const int* dsrc) {
        half4 va[4], vb[4];
        #pragma unroll
        for (int g2 = 0; g2 < 4; ++g2) {
            va[g2] = *(const half4*)(U + mtAddr(colA, g2));
            vb[g2] = *(const half4*)(U + mtAddr(colB, g2));
        }
        int dArr[16];
        *(int4*)(dArr)      = *(const int4*)(dsrc);
        *(int4*)(dArr + 4)  = *(const int4*)(dsrc + 4);
        *(int4*)(dArr + 8)  = *(const int4*)(dsrc + 8);
        *(int4*)(dArr + 12) = *(const int4*)(dsrc + 12);
        #pragma unroll
        for (int r = 0; r < 16; ++r) {
            int dd = dArr[r];
            float v0 = (float)va[r >> 2][r & 3];
            float v1 = (float)vb[r >> 2][r & 3];
            if (dd != prev) {   // wave-uniform branch
                if (prev >= 0) {
                    unsafeAtomicAdd(&h[(size_t)prev * 128 + colA], carry0);
                    unsafeAtomicAdd(&h[(size_t)prev * 128 + colB], carry1);
                }
                prev = dd; carry0 = v0; carry1 = v1;
            } else { carry0 += v0; carry1 += v1; }
        }
    };

    // balanced partition: 25000 pairs over 4096 waves (6 or 7 each)
    int wgid = blockIdx.x * 16 + wv;
    int extra = wgid < 424 ? wgid : 424;
    int p0 = wgid * 6 + extra;
    int p1 = p0 + 6 + (wgid < 424 ? 1 : 0);

    // prologue: 32 records of pair p0 on lanes 0..31
    uint4 pk = {0u, 0u, 0u, 0u};
    if (lane < 32) pk = packE[(size_t)p0 * 32 + lane];

    for (int cp = p0; cp < p1; ++cp) {
        bool hasNext = (cp + 1 < p1);
        // ---- distribute both chunks' records ------------------------------
        int   ety0 = __shfl((int)pk.y, trow);
        int   ety1 = __shfl((int)pk.y, 16 + trow);
        int   src0 = __shfl((int)pk.x, n16);
        int   src1 = __shfl((int)pk.x, 16 + n16);
        float d0   = __shfl(__uint_as_float(pk.w), n16);
        float d1   = __shfl(__uint_as_float(pk.w), 16 + n16);
        if (lane < 32) dW[lane] = (int)pk.z;

        half8 a2e0[4];
        // ================= chunk 0 (full R11 pipeline to a2e0) =============
        {
            // T0 stage (drained into LDS)
            {
                const uint4* Tp = (const uint4*)(T + (size_t)ety0 * 128 + tsub * 32);
                uint4 t0 = Tp[0], t1 = Tp[1], t2 = Tp[2], t3 = Tp[3];
                uint4* ub = (uint4*)(U + trow * 136 + tsub * 32);
                ub[0] = t0; ub[1] = t1; ub[2] = t2; ub[3] = t3;
            }
            __builtin_amdgcn_sched_barrier(0);
            // P0 + next pk
            half8 pA[4];
            {
                const f16* Pr = P + (size_t)src0 * 128 + q * 8;
                #pragma unroll
                for (int kk = 0; kk < 4; ++kk) pA[kk] = *(const half8*)(Pr + kk * 32);
            }
            // rbf0 (VALU overlaps P latency)
            half8 ar;
            #pragma unroll
            for (int j = 0; j < 8; ++j) {
                int k = q * 8 + j;
                float c = (float)k * (10.0f / 29.0f);
                float df = d0 - c;
                ar[j] = (f16)((k < 30) ? __expf(-df * df * invgap) : 0.0f);
            }
            // B0
            #pragma unroll
            for (int f = 0; f < 8; ++f) {
                f16* up = U + n16 * 136 + f * 16 + q * 4;
                half4 tv = *(const half4*)up;
                floatx4 c4 = {(float)tv[0], (float)tv[1], (float)tv[2], (float)tv[3]};
                half8 aw = *(const half8*)(W1rT + (f * 16 + n16) * 40 + q * 8);
                c4 = __builtin_amdgcn_mfma_f32_16x16x32_f16(aw, ar, c4, 0, 0, 0);
                half4 uv;
                #pragma unroll
                for (int i = 0; i < 4; ++i) uv[i] = (f16)fmaxf(c4[i], 0.0f);
                *(half4*)up = uv;
            }
            // C0
            half8 a2[4];
            #pragma unroll
            for (int kk = 0; kk < 4; ++kk)
                a2[kk] = *(const half8*)(U + n16 * 136 + kk * 32 + q * 8);
            #pragma unroll
            for (int f = 0; f < 8; ++f) {
                floatx4 acc = *(const floatx4*)(sbe2 + f * 16 + q * 4);
                #pragma unroll
                for (int kk = 0; kk < 4; ++kk) {
                    half8 aw = *(const half8*)(W2T + (f * 16 + n16) * 136 + kk * 32 + q * 8);
                    acc = __builtin_amdgcn_mfma_f32_16x16x32_f16(aw, a2[kk], acc, 0, 0, 0);
                }
                half4 ev;
                #pragma unroll
                for (int i = 0; i < 4; ++i) ev[i] = (f16)acc[i];
                *(half4*)(U + n16 * 136 + f * 16 + q * 4) = ev;
            }
            // a2e0 = ep0 ⊙ P0
            #pragma unroll
            for (int kk = 0; kk < 4; ++kk) {
                half8 e = *(const half8*)(U + n16 * 136 + kk * 32 + q * 8);
                a2e0[kk] = e * pA[kk];
            }
        }
        __builtin_amdgcn_sched_barrier(0);

        half8 a2e1[4];
        // ================= chunk 1 =========================================
        {
            // T1 stage (in-wave DS order: after ep0 reads above)
            {
                const uint4* Tp = (const uint4*)(T + (size_t)ety1 * 128 + tsub * 32);
                uint4 t0 = Tp[0], t1 = Tp[1], t2 = Tp[2], t3 = Tp[3];
                uint4* ub = (uint4*)(U + trow * 136 + tsub * 32);
                ub[0] = t0; ub[1] = t1; ub[2] = t2; ub[3] = t3;
            }
            __builtin_amdgcn_sched_barrier(0);
            // P1 + next pk
            half8 pA[4];
            {
                const f16* Pr = P + (size_t)src1 * 128 + q * 8;
                #pragma unroll
                for (int kk = 0; kk < 4; ++kk) pA[kk] = *(const half8*)(Pr + kk * 32);
            }
            uint4 pkn = {0u, 0u, 0u, 0u};
            if (hasNext && lane < 32) pkn = packE[(size_t)(cp + 1) * 32 + lane];
            // rbf1
            half8 ar;
            #pragma unroll
            for (int j = 0; j < 8; ++j) {
                int k = q * 8 + j;
                float c = (float)k * (10.0f / 29.0f);
                float df = d1 - c;
                ar[j] = (f16)((k < 30) ? __expf(-df * df * invgap) : 0.0f);
            }
            // B1
            #pragma unroll
            for (int f = 0; f < 8; ++f) {
                f16* up = U + n16 * 136 + f * 16 + q * 4;
                half4 tv = *(const half4*)up;
                floatx4 c4 = {(float)tv[0], (float)tv[1], (float)tv[2], (float)tv[3]};
                half8 aw = *(const half8*)(W1rT + (f * 16 + n16) * 40 + q * 8);
                c4 = __builtin_amdgcn_mfma_f32_16x16x32_f16(aw, ar, c4, 0, 0, 0);
                half4 uv;
                #pragma unroll
                for (int i = 0; i < 4; ++i) uv[i] = (f16)fmaxf(c4[i], 0.0f);
                *(half4*)up = uv;
            }
            // C1
            half8 a2[4];
            #pragma unroll
            for (int kk = 0; kk < 4; ++kk)
                a2[kk] = *(const half8*)(U + n16 * 136 + kk * 32 + q * 8);
            #pragma unroll
            for (int f = 0; f < 8; ++f) {
                floatx4 acc = *(const floatx4*)(sbe2 + f * 16 + q * 4);
                #pragma unroll
                for (int kk = 0; kk < 4; ++kk) {
                    half8 aw = *(const half8*)(W2T + (f * 16 + n16) * 136 + kk * 32 + q * 8);
                    acc = __builtin_amdgcn_mfma_f32_16x16x32_f16(aw, a2[kk], acc, 0, 0, 0);
                }
                half4 ev;
                #pragma unroll
                for (int i = 0; i < 4; ++i) ev[i] = (f16)acc[i];
                *(half4*)(U + n16 * 136 + f * 16 + q * 4) = ev;
            }
            // a2e1 = ep1 ⊙ P1
            #pragma unroll
            for (int kk = 0; kk < 4; ++kk) {
                half8 e = *(const half8*)(U + n16 * 136 + kk * 32 + q * 8);
                a2e1[kk] = e * pA[kk];
            }
            pk = pkn;
        }

        // ---- E shared: one WcT fragment read feeds TWO MFMAs --------------
        half4 mv1r[8];
        #pragma unroll
        for (int f = 0; f < 8; ++f) {
            float bb = sbcv[f];
            floatx4 m0 = {bb, bb, bb, bb};
            floatx4 m1 = {bb, bb, bb, bb};
            #pragma unroll
            for (int kk = 0; kk < 4; ++kk) {
                half8 bw = *(const half8*)(WcT + (f * 16 + n16) * 136 + kk * 32 + q * 8);
                m0 = __builtin_amdgcn_mfma_f32_16x16x32_f16(a2e0[kk], bw, m0, 0, 0, 0);
                m1 = __builtin_amdgcn_mfma_f32_16x16x32_f16(a2e1[kk], bw, m1, 0, 0, 0);
            }
            int c = f * 16 + n16;
            half4 x0;
            #pragma unroll
            for (int i = 0; i < 4; ++i) x0[i] = (f16)fast_tanh(m0[i]);
            *(half4*)(U + mtAddr(c, q)) = x0;     // mT0
            half4 x1;
            #pragma unroll
            for (int i = 0; i < 4; ++i) x1[i] = (f16)fast_tanh(m1[i]);
            mv1r[f] = x1;                          // m1 parked (16 regs, short-lived)
        }

        // ---- F0; then mT1 from regs; F1 -----------------------------------
        segreduce(dW);
        #pragma unroll
        for (int f = 0; f < 8; ++f)
            *(half4*)(U + mtAddr(f * 16 + n16, q)) = mv1r[f];
        segreduce(dW + 16);

        __builtin_amdgcn_sched_barrier(0);   // no cross-iteration load hoisting
    }
    if (prev >= 0) {
        unsafeAtomicAdd(&h[(size_t)prev * 128 + colA], carry0);
        unsafeAtomicAdd(&h[(size_t)prev * 128 + colB], carry1);
    }
}

// fused readout: hr = relu(h@Wr1+br1)·Wr2 + br2, out[gid] += hr  (per row)
__global__ __launch_bounds__(1024, 4) void readout_k(
        const float* __restrict__ X, int M,
        const float* __restrict__ W1, const float* __restrict__ b1,
        const float* __restrict__ Wr2, const float* __restrict__ br2,
        const int* __restrict__ gid, float* __restrict__ out) {
    __shared__ f16 W1T[128 * 136];
    __shared__ f16 xBuf[256 * 136];
    __shared__ float bias1[128];
    __shared__ float sWr2[128];
    int tid = threadIdx.x;

    stage_WT(W1, W1T, tid, 1024);
    if (tid < 128) { bias1[tid] = b1[tid]; sWr2[tid] = Wr2[tid]; }

    int r0 = blockIdx.x * 256;
    for (int it = 0; it < 8; ++it) {
        int row = it * 32 + (tid >> 5);
        int c4 = (tid & 31) * 4;
        int gr = r0 + row;
        floatx4 x = {0.0f, 0.0f, 0.0f, 0.0f};
        if (gr < M) x = *(const floatx4*)(X + (size_t)gr * 128 + c4);
        half4 xh;
        xh[0] = (f16)x[0]; xh[1] = (f16)x[1]; xh[2] = (f16)x[2]; xh[3] = (f16)x[3];
        *(half4*)(xBuf + row * 136 + c4) = xh;
    }
    __syncthreads();

    int lane = tid & 63, wv = tid >> 6;
    int R = wv * 16;
    int n16 = lane & 15, q = lane >> 4;

    half8 a[4];
    #pragma unroll
    for (int kk = 0; kk < 4; ++kk)
        a[kk] = *(const half8*)(xBuf + (R + n16) * 136 + kk * 32 + q * 8);

    floatx4 acc[8];
    #pragma unroll
    for (int f = 0; f < 8; ++f) {
        float bb = bias1[f * 16 + n16];
        acc[f] = (floatx4){bb, bb, bb, bb};
        #pragma unroll
        for (int kk = 0; kk < 4; ++kk) {
            half8 b = *(const half8*)(W1T + (f * 16 + n16) * 136 + kk * 32 + q * 8);
            acc[f] = __builtin_amdgcn_mfma_f32_16x16x32_f16(a[kk], b, acc[f], 0, 0, 0);
        }
    }

    float s[4];
    #pragma unroll
    for (int i = 0; i < 4; ++i) {
        float t = 0.0f;
        #pragma unroll
        for (int f = 0; f < 8; ++f)
            t += fmaxf(acc[f][i], 0.0f) * sWr2[f * 16 + n16];
        #pragma unroll
        for (int m = 1; m < 16; m <<= 1) t += __shfl_xor(t, m);
        s[i] = t;
    }

    if (n16 == 0) {
        float br2v = br2[0];
        float t = 0.0f; int g = -1;
        #pragma unroll
        for (int i = 0; i < 4; ++i) {
            int gr = r0 + R + q * 4 + i;
            if (gr < M) {
                int gi = gid[gr];
                float si = s[i] + br2v;
                if (gi == g) t += si;
                else { if (g >= 0) unsafeAtomicAdd(&out[g], t); g = gi; t = si; }
            }
        }
        if (g >= 0) unsafeAtomicAdd(&out[g], t);
    }
}

extern "C" void kernel_launch(void* const* d_in, const int* in_sizes, int n_in,
                              void* d_out, int out_size, void* d_ws, size_t ws_size,
                              hipStream_t stream) {
    (void)in_sizes; (void)n_in; (void)ws_size;
    const int*   node_types = (const int*)d_in[0];
    const int*   edge_types = (const int*)d_in[1];
    const int*   src        = (const int*)d_in[2];
    const int*   dst        = (const int*)d_in[3];
    const int*   graph_ids  = (const int*)d_in[4];
    const float* distances  = (const float*)d_in[5];
    const float* node_emb   = (const float*)d_in[7];
    const float* edge_emb   = (const float*)d_in[8];
    const float* Wn1 = (const float*)d_in[9];
    const float* bn1 = (const float*)d_in[10];
    const float* Wn2 = (const float*)d_in[11];
    const float* bn2 = (const float*)d_in[12];
    const float* We1 = (const float*)d_in[13];
    const float* be1 = (const float*)d_in[14];
    const float* We2 = (const float*)d_in[15];
    const float* be2 = (const float*)d_in[16];
    const float* Wc  = (const float*)d_in[17];
    const float* bc  = (const float*)d_in[18];
    const float* Wr1 = (const float*)d_in[19];
    const float* br1 = (const float*)d_in[20];
    const float* Wr2 = (const float*)d_in[21];
    const float* br2 = (const float*)d_in[22];

    char* w = (char*)d_ws;
    auto carve = [&](size_t bytes) { char* p = w; w += (bytes + 255) & ~(size_t)255; return p; };
    float* h        = (float*)carve((size_t)NNODES * 128 * 4);
    f16*   P        = (f16*)  carve((size_t)NNODES * 128 * 2);
    f16*   T        = (f16*)  carve((size_t)500 * 128 * 2);
    int*   rowStart = (int*)  carve((size_t)(NNODES + 1) * 4);
    int*   cnt      = (int*)  carve((size_t)NNODES * 4);
    int*   blockSum = (int*)  carve((size_t)64 * 4);
    uint4* packE    = (uint4*)carve((size_t)NEDGES * 16);

    float* out = (float*)d_out;
    const int NB1 = (NNODES + 1023) / 1024;   // 49

    init_k<<<(NNODES + 255) / 256, 256, 0, stream>>>(out, out_size, cnt);
    hist_k<<<NEDGES / 256, 256, 0, stream>>>(dst, cnt);
    scan1_k<<<NB1, 1024, 0, stream>>>(cnt, rowStart, blockSum);
    scan2_k<<<1, 64, 0, stream>>>(blockSum, NB1);
    scan3_k<<<NB1, 1024, 0, stream>>>(rowStart, blockSum, cnt);
    scatter_k<<<NEDGES / 256, 256, 0, stream>>>(src, edge_types, dst, distances,
                                                rowStart, cnt, packE);
    gather_h<<<(NNODES * 32 + 255) / 256, 256, 0, stream>>>(node_types, node_emb, h);

    for (int i = 0; i < 3; ++i) {
        mlp_kernel<2><<<(500 + 255) / 256, 1024, 0, stream>>>(
            edge_emb, 500, We1 + (size_t)i * 158 * 128, be1 + i * 128, nullptr, nullptr, T);
        mlp_kernel<0><<<(NNODES + 255) / 256, 1024, 0, stream>>>(
            h, NNODES, Wn1 + (size_t)i * 128 * 128, bn1 + i * 128,
            Wn2 + (size_t)i * 128 * 128, bn2 + i * 128, P);
        edge_kernel<<<256, 1024, 0, stream>>>(
            packE, P, T,
            We1 + (size_t)i * 158 * 128,
            We2 + (size_t)i * 128 * 128, be2 + i * 128,
            Wc + (size_t)i * 128 * 128, bc + i * 128, h);
    }

    readout_k<<<(NNODES + 255) / 256, 1024, 0, stream>>>(
        h, NNODES, Wr1, br1, Wr2, br2, graph_ids, out);
}

// Round 14
// 720.876 us; speedup vs baseline: 1.0991x; 1.0991x over previous
//
#include <hip/hip_runtime.h>
#include <stdint.h>

#define NNODES 50000
#define NEDGES 800000
#define NGRAPH 100
#define NCHUNK (NEDGES / 16)   // 50000 16-edge chunks
#define NWAVES 4096            // 256 blocks x 16 waves

typedef _Float16 f16;
typedef __attribute__((ext_vector_type(8))) _Float16 half8;
typedef __attribute__((ext_vector_type(4))) _Float16 half4;
typedef __attribute__((ext_vector_type(4))) float floatx4;

// stage 128x128 fp32 row-major W[k][n] -> LDS WT[n][136 pad] fp16, float4 loads
__device__ __forceinline__ void stage_WT(const float* __restrict__ W, f16* WT,
                                         int tid, int nthr) {
    for (int idx = tid; idx < 128 * 32; idx += nthr) {
        int k = idx >> 5, n4 = (idx & 31) * 4;
        floatx4 v = *(const floatx4*)(W + k * 128 + n4);
        WT[(n4 + 0) * 136 + k] = (f16)v[0];
        WT[(n4 + 1) * 136 + k] = (f16)v[1];
        WT[(n4 + 2) * 136 + k] = (f16)v[2];
        WT[(n4 + 3) * 136 + k] = (f16)v[3];
    }
}

__device__ __forceinline__ float fast_tanh(float x) {
    x = fminf(fmaxf(x, -15.0f), 15.0f);
    float e2 = __expf(2.0f * x);
    return (e2 - 1.0f) * __builtin_amdgcn_rcpf(e2 + 1.0f);
}

// transposed-m: column c owns f16 elements [c*16, c*16+16); row groups of 4
// rotated by (c>>2) to spread banks. Bijective per column -> collision-free.
__device__ __forceinline__ int mtAddr(int c, int rgroup) {
    return c * 16 + ((((c >> 2) + rgroup) & 3) << 2);
}

__global__ void init_k(float* out, int osz, int* cnt) {
    int i = blockIdx.x * 256 + threadIdx.x;
    if (i < osz) out[i] = 0.0f;
    if (i < NNODES) cnt[i] = 0;
}

__global__ void hist_k(const int* __restrict__ dst, int* __restrict__ cnt) {
    int e = blockIdx.x * 256 + threadIdx.x;
    if (e < NEDGES) atomicAdd(&cnt[dst[e]], 1);
}

__global__ __launch_bounds__(1024) void scan1_k(const int* __restrict__ cnt,
                                                int* __restrict__ rowStart,
                                                int* __restrict__ blockSum) {
    __shared__ int buf[1024];
    int tid = threadIdx.x;
    int i = blockIdx.x * 1024 + tid;
    int v = (i < NNODES) ? cnt[i] : 0;
    buf[tid] = v;
    __syncthreads();
    for (int off = 1; off < 1024; off <<= 1) {
        int t = (tid >= off) ? buf[tid - off] : 0;
        __syncthreads();
        buf[tid] += t;
        __syncthreads();
    }
    if (i < NNODES) rowStart[i] = buf[tid] - v;
    if (tid == 1023) blockSum[blockIdx.x] = buf[1023];
}

__global__ void scan2_k(int* __restrict__ blockSum, int nb) {
    if (threadIdx.x == 0) {
        int run = 0;
        for (int b = 0; b < nb; ++b) { int s = blockSum[b]; blockSum[b] = run; run += s; }
    }
}

__global__ __launch_bounds__(1024) void scan3_k(int* __restrict__ rowStart,
                                                const int* __restrict__ blockSum,
                                                int* __restrict__ cnt) {
    int i = blockIdx.x * 1024 + threadIdx.x;
    if (i < NNODES) { rowStart[i] += blockSum[blockIdx.x]; cnt[i] = 0; }
    if (i == 0) rowStart[NNODES] = NEDGES;
}

__global__ void scatter_k(const int* __restrict__ src, const int* __restrict__ et,
                          const int* __restrict__ dst, const float* __restrict__ dist,
                          const int* __restrict__ rowStart, int* __restrict__ cnt,
                          uint4* __restrict__ packE) {
    int e = blockIdx.x * 256 + threadIdx.x;
    if (e >= NEDGES) return;
    int d = dst[e];
    int pos = rowStart[d] + atomicAdd(&cnt[d], 1);
    uint4 pk;
    pk.x = (unsigned)src[e];
    pk.y = (unsigned)et[e];
    pk.z = (unsigned)d;
    pk.w = __float_as_uint(dist[e]);
    packE[pos] = pk;
}

__global__ void gather_h(const int* __restrict__ nt, const float* __restrict__ emb,
                         float* __restrict__ h) {
    int i = blockIdx.x * 256 + threadIdx.x;
    int row = i >> 5, c4 = (i & 31) * 4;
    if (row < NNODES)
        *(floatx4*)(h + row * 128 + c4) = *(const floatx4*)(emb + nt[row] * 128 + c4);
}

// MODE 0: relu(X@W1+b1)@W2+b2 -> Out f16   MODE 2: X@W1+b1 -> Out f16
// Operand-swapped MFMAs -> feature-contiguous C-layout, all LDS b64/b128.
template <int MODE>
__global__ __launch_bounds__(1024, 4) void mlp_kernel(
        const float* __restrict__ X, int M,
        const float* __restrict__ W1, const float* __restrict__ b1,
        const float* __restrict__ W2, const float* __restrict__ b2,
        f16* __restrict__ Out) {
    __shared__ f16 W1T[128 * 136];
    __shared__ f16 W2T[(MODE == 0) ? 128 * 136 : 8];
    __shared__ f16 xBuf[256 * 136];
    __shared__ float bias1[128];
    __shared__ float bias2[128];
    int tid = threadIdx.x;

    stage_WT(W1, W1T, tid, 1024);
    if (MODE == 0) stage_WT(W2, W2T, tid, 1024);
    if (tid < 128) { bias1[tid] = b1[tid]; bias2[tid] = (MODE == 0) ? b2[tid] : 0.0f; }

    int r0 = blockIdx.x * 256;
    for (int it = 0; it < 8; ++it) {
        int row = it * 32 + (tid >> 5);
        int c4 = (tid & 31) * 4;
        int gr = r0 + row;
        floatx4 x = {0.0f, 0.0f, 0.0f, 0.0f};
        if (gr < M) x = *(const floatx4*)(X + (size_t)gr * 128 + c4);
        half4 xh;
        xh[0] = (f16)x[0]; xh[1] = (f16)x[1]; xh[2] = (f16)x[2]; xh[3] = (f16)x[3];
        *(half4*)(xBuf + row * 136 + c4) = xh;
    }
    __syncthreads();

    int lane = tid & 63, wv = tid >> 6;
    int R = wv * 16;
    int n16 = lane & 15, q = lane >> 4;
    int gr = r0 + R + n16;

    half8 a[4];
    #pragma unroll
    for (int kk = 0; kk < 4; ++kk)
        a[kk] = *(const half8*)(xBuf + (R + n16) * 136 + kk * 32 + q * 8);

    #pragma unroll
    for (int f = 0; f < 8; ++f) {
        floatx4 acc = *(const floatx4*)(bias1 + f * 16 + q * 4);
        #pragma unroll
        for (int kk = 0; kk < 4; ++kk) {
            half8 aw = *(const half8*)(W1T + (f * 16 + n16) * 136 + kk * 32 + q * 8);
            acc = __builtin_amdgcn_mfma_f32_16x16x32_f16(aw, a[kk], acc, 0, 0, 0);
        }
        if (MODE == 0) {
            half4 y;
            #pragma unroll
            for (int i = 0; i < 4; ++i) y[i] = (f16)fmaxf(acc[i], 0.0f);
            *(half4*)(xBuf + (R + n16) * 136 + f * 16 + q * 4) = y;
        } else {
            half4 o;
            #pragma unroll
            for (int i = 0; i < 4; ++i) o[i] = (f16)acc[i];
            if (gr < M) *(half4*)(Out + (size_t)gr * 128 + f * 16 + q * 4) = o;
        }
    }

    if (MODE == 0) {
        #pragma unroll
        for (int kk = 0; kk < 4; ++kk)
            a[kk] = *(const half8*)(xBuf + (R + n16) * 136 + kk * 32 + q * 8);
        #pragma unroll
        for (int f = 0; f < 8; ++f) {
            floatx4 acc = *(const floatx4*)(bias2 + f * 16 + q * 4);
            #pragma unroll
            for (int kk = 0; kk < 4; ++kk) {
                half8 aw = *(const half8*)(W2T + (f * 16 + n16) * 136 + kk * 32 + q * 8);
                acc = __builtin_amdgcn_mfma_f32_16x16x32_f16(aw, a[kk], acc, 0, 0, 0);
            }
            half4 o;
            #pragma unroll
            for (int i = 0; i < 4; ++i) o[i] = (f16)acc[i];
            if (gr < M) *(half4*)(Out + (size_t)gr * 128 + f * 16 + q * 4) = o;
        }
    }
}

// ---------------------------------------------------------------------------
// Barrier-free edge kernel (R11 — session optimum). 16 waves/block, 1
// block/CU, wave-local 16-edge chunks, all LDS ops b64/b128 (operand-swapped
// MFMAs). MEMORY SCHEDULE ENFORCED WITH sched_barrier(0): the compiler
// otherwise pipelines next-chunk T/P gathers across iterations (R8/R10:
// FETCH 223/226 MB), thrashing the 4 MB per-XCD L2. Fenced: FETCH 80.6 MB,
// WRITE 26.9 MB, 142 us/layer. Pair/tile variants (R9/R12/R13) all spilled
// or thrashed — this structure is the measured local optimum.
// ---------------------------------------------------------------------------
__global__ __launch_bounds__(1024, 4) void edge_kernel(
        const uint4* __restrict__ packE,
        const f16* __restrict__ P, const f16* __restrict__ T,
        const float* __restrict__ We1,
        const float* __restrict__ We2, const float* __restrict__ be2,
        const float* __restrict__ Wc,  const float* __restrict__ bc,
        float* __restrict__ h) {
    __shared__ f16 W2T[128 * 136];       // 34816 B
    __shared__ f16 WcT[128 * 136];       // 34816 B
    __shared__ f16 W1rT[128 * 40];       // 10240 B
    __shared__ f16 Uall[16 * 2176];      // 69632 B : per-wave 16x136 (T/u/ep) then mT
    __shared__ float sbe2[128], sbc[128];
    __shared__ int dstW[16][16];
    // total ~151.5 KB -> 1 block/CU, 16 waves

    int tid = threadIdx.x;
    stage_WT(We2, W2T, tid, 1024);
    stage_WT(Wc,  WcT, tid, 1024);
    for (int idx = tid; idx < 128 * 32; idx += 1024) {
        int n = idx >> 5, kr = idx & 31;
        W1rT[n * 40 + kr] = (kr < 30) ? (f16)We1[(128 + kr) * 128 + n] : (f16)0.0f;
    }
    if (tid < 128) { sbe2[tid] = be2[tid]; sbc[tid] = bc[tid]; }
    __syncthreads();    // weights ready; the ONLY block barrier

    int lane = tid & 63, wv = tid >> 6;
    f16* U = Uall + wv * 2176;
    int* dW = dstW[wv];
    int n16 = lane & 15, q = lane >> 4;
    const float invgap = 29.0f / 10.0f;
    int colA = lane, colB = lane + 64;
    int tsub = lane & 3, trow = lane >> 2;

    float sbcv[8];
    #pragma unroll
    for (int f = 0; f < 8; ++f) sbcv[f] = sbc[f * 16 + n16];

    // balanced stripe partition: 50000 chunks over 4096 waves (12 or 13 each)
    int wgid = blockIdx.x * 16 + wv;
    int extra = wgid < 848 ? wgid : 848;
    int c0 = wgid * 12 + extra;
    int c1 = c0 + 12 + (wgid < 848 ? 1 : 0);

    float carry0 = 0.0f, carry1 = 0.0f;
    int prev = -1;

    // prologue: pk for chunk c0
    uint4 pk = {0u, 0u, 0u, 0u};
    if (lane < 16) pk = packE[(size_t)c0 * 16 + lane];

    for (int ch = c0; ch < c1; ++ch) {
        bool hasNext = (ch + 1 < c1);
        // ---- distribute current records -----------------------------------
        int   ety  = __shfl((int)pk.y, trow);
        int   srcv = __shfl((int)pk.x, n16);
        float dcur = __shfl(__uint_as_float(pk.w), n16);
        if (lane < 16) dW[lane] = (int)pk.z;

        // ---- T loads, drained into LDS (phase A) --------------------------
        {
            const uint4* Tp = (const uint4*)(T + (size_t)ety * 128 + tsub * 32);
            uint4 tr0 = Tp[0], tr1 = Tp[1], tr2 = Tp[2], tr3 = Tp[3];
            uint4* ub = (uint4*)(U + trow * 136 + tsub * 32);
            ub[0] = tr0; ub[1] = tr1; ub[2] = tr2; ub[3] = tr3;
        }
        __builtin_amdgcn_sched_barrier(0);   // T drained before P issues

        // ---- NOW issue P loads (T no longer in flight) --------------------
        half8 pA0, pA1, pA2, pA3;
        {
            const f16* Pr = P + (size_t)srcv * 128 + q * 8;
            pA0 = *(const half8*)(Pr);
            pA1 = *(const half8*)(Pr + 32);
            pA2 = *(const half8*)(Pr + 64);
            pA3 = *(const half8*)(Pr + 96);
        }
        uint4 pkn = {0u, 0u, 0u, 0u};
        if (hasNext && lane < 16) pkn = packE[(size_t)(ch + 1) * 16 + lane];

        // ---- rbf in regs (VALU overlaps P latency) ------------------------
        half8 ar;
        #pragma unroll
        for (int j = 0; j < 8; ++j) {
            int k = q * 8 + j;
            float c = (float)k * (10.0f / 29.0f);
            float df = dcur - c;
            ar[j] = (f16)((k < 30) ? __expf(-df * df * invgap) : 0.0f);
        }

        // ---- B: u^T = relu(W1r^T @ rbf^T + T^T)  (all b64/b128) -----------
        #pragma unroll
        for (int f = 0; f < 8; ++f) {
            f16* up = U + n16 * 136 + f * 16 + q * 4;
            half4 tv = *(const half4*)up;
            floatx4 c4 = {(float)tv[0], (float)tv[1], (float)tv[2], (float)tv[3]};
            half8 aw = *(const half8*)(W1rT + (f * 16 + n16) * 40 + q * 8);
            c4 = __builtin_amdgcn_mfma_f32_16x16x32_f16(aw, ar, c4, 0, 0, 0);
            half4 uv;
            #pragma unroll
            for (int i = 0; i < 4; ++i) uv[i] = (f16)fmaxf(c4[i], 0.0f);
            *(half4*)up = uv;
        }

        // ---- C: ep^T = W2^T @ u^T + be2 -----------------------------------
        half8 a2[4];
        #pragma unroll
        for (int kk = 0; kk < 4; ++kk)
            a2[kk] = *(const half8*)(U + n16 * 136 + kk * 32 + q * 8);
        #pragma unroll
        for (int f = 0; f < 8; ++f) {
            floatx4 acc = *(const floatx4*)(sbe2 + f * 16 + q * 4);
            #pragma unroll
            for (int kk = 0; kk < 4; ++kk) {
                half8 aw = *(const half8*)(W2T + (f * 16 + n16) * 136 + kk * 32 + q * 8);
                acc = __builtin_amdgcn_mfma_f32_16x16x32_f16(aw, a2[kk], acc, 0, 0, 0);
            }
            half4 ev;
            #pragma unroll
            for (int i = 0; i < 4; ++i) ev[i] = (f16)acc[i];
            *(half4*)(U + n16 * 136 + f * 16 + q * 4) = ev;
        }

        // ---- E: m = tanh((P ⊙ ep) @ Wc + bc); write mT (b64, swizzled) ----
        {
            half8 e0 = *(const half8*)(U + n16 * 136 + 0 * 32 + q * 8);
            half8 e1 = *(const half8*)(U + n16 * 136 + 1 * 32 + q * 8);
            half8 e2 = *(const half8*)(U + n16 * 136 + 2 * 32 + q * 8);
            half8 e3 = *(const half8*)(U + n16 * 136 + 3 * 32 + q * 8);
            a2[0] = e0 * pA0; a2[1] = e1 * pA1; a2[2] = e2 * pA2; a2[3] = e3 * pA3;
        }
        #pragma unroll
        for (int f = 0; f < 8; ++f) {
            float bb = sbcv[f];
            floatx4 acc = {bb, bb, bb, bb};
            #pragma unroll
            for (int kk = 0; kk < 4; ++kk) {
                half8 b = *(const half8*)(WcT + (f * 16 + n16) * 136 + kk * 32 + q * 8);
                acc = __builtin_amdgcn_mfma_f32_16x16x32_f16(a2[kk], b, acc, 0, 0, 0);
            }
            int c = f * 16 + n16;
            half4 mv;
            #pragma unroll
            for (int i = 0; i < 4; ++i) mv[i] = (f16)fast_tanh(acc[i]);
            *(half4*)(U + mtAddr(c, q)) = mv;
        }

        // ---- F: per-col segment reduce with cross-chunk carry -------------
        {
            half4 va[4], vb[4];
            #pragma unroll
            for (int g2 = 0; g2 < 4; ++g2) {
                va[g2] = *(const half4*)(U + mtAddr(colA, g2));
                vb[g2] = *(const half4*)(U + mtAddr(colB, g2));
            }
            int dArr[16];
            *(int4*)(dArr)      = *(const int4*)(dW);
            *(int4*)(dArr + 4)  = *(const int4*)(dW + 4);
            *(int4*)(dArr + 8)  = *(const int4*)(dW + 8);
            *(int4*)(dArr + 12) = *(const int4*)(dW + 12);
            #pragma unroll
            for (int r = 0; r < 16; ++r) {
                int dd = dArr[r];
                float v0 = (float)va[r >> 2][r & 3];
                float v1 = (float)vb[r >> 2][r & 3];
                if (dd != prev) {   // wave-uniform branch
                    if (prev >= 0) {
                        unsafeAtomicAdd(&h[(size_t)prev * 128 + colA], carry0);
                        unsafeAtomicAdd(&h[(size_t)prev * 128 + colB], carry1);
                    }
                    prev = dd; carry0 = v0; carry1 = v1;
                } else { carry0 += v0; carry1 += v1; }
            }
        }
        pk = pkn;
        __builtin_amdgcn_sched_barrier(0);   // no cross-iteration load hoisting
    }
    if (prev >= 0) {
        unsafeAtomicAdd(&h[(size_t)prev * 128 + colA], carry0);
        unsafeAtomicAdd(&h[(size_t)prev * 128 + colB], carry1);
    }
}

// fused readout: hr = relu(h@Wr1+br1)·Wr2 + br2, out[gid] += hr  (per row)
__global__ __launch_bounds__(1024, 4) void readout_k(
        const float* __restrict__ X, int M,
        const float* __restrict__ W1, const float* __restrict__ b1,
        const float* __restrict__ Wr2, const float* __restrict__ br2,
        const int* __restrict__ gid, float* __restrict__ out) {
    __shared__ f16 W1T[128 * 136];
    __shared__ f16 xBuf[256 * 136];
    __shared__ float bias1[128];
    __shared__ float sWr2[128];
    int tid = threadIdx.x;

    stage_WT(W1, W1T, tid, 1024);
    if (tid < 128) { bias1[tid] = b1[tid]; sWr2[tid] = Wr2[tid]; }

    int r0 = blockIdx.x * 256;
    for (int it = 0; it < 8; ++it) {
        int row = it * 32 + (tid >> 5);
        int c4 = (tid & 31) * 4;
        int gr = r0 + row;
        floatx4 x = {0.0f, 0.0f, 0.0f, 0.0f};
        if (gr < M) x = *(const floatx4*)(X + (size_t)gr * 128 + c4);
        half4 xh;
        xh[0] = (f16)x[0]; xh[1] = (f16)x[1]; xh[2] = (f16)x[2]; xh[3] = (f16)x[3];
        *(half4*)(xBuf + row * 136 + c4) = xh;
    }
    __syncthreads();

    int lane = tid & 63, wv = tid >> 6;
    int R = wv * 16;
    int n16 = lane & 15, q = lane >> 4;

    half8 a[4];
    #pragma unroll
    for (int kk = 0; kk < 4; ++kk)
        a[kk] = *(const half8*)(xBuf + (R + n16) * 136 + kk * 32 + q * 8);

    floatx4 acc[8];
    #pragma unroll
    for (int f = 0; f < 8; ++f) {
        float bb = bias1[f * 16 + n16];
        acc[f] = (floatx4){bb, bb, bb, bb};
        #pragma unroll
        for (int kk = 0; kk < 4; ++kk) {
            half8 b = *(const half8*)(W1T + (f * 16 + n16) * 136 + kk * 32 + q * 8);
            acc[f] = __builtin_amdgcn_mfma_f32_16x16x32_f16(a[kk], b, acc[f], 0, 0, 0);
        }
    }

    float s[4];
    #pragma unroll
    for (int i = 0; i < 4; ++i) {
        float t = 0.0f;
        #pragma unroll
        for (int f = 0; f < 8; ++f)
            t += fmaxf(acc[f][i], 0.0f) * sWr2[f * 16 + n16];
        #pragma unroll
        for (int m = 1; m < 16; m <<= 1) t += __shfl_xor(t, m);
        s[i] = t;
    }

    if (n16 == 0) {
        float br2v = br2[0];
        float t = 0.0f; int g = -1;
        #pragma unroll
        for (int i = 0; i < 4; ++i) {
            int gr = r0 + R + q * 4 + i;
            if (gr < M) {
                int gi = gid[gr];
                float si = s[i] + br2v;
                if (gi == g) t += si;
                else { if (g >= 0) unsafeAtomicAdd(&out[g], t); g = gi; t = si; }
            }
        }
        if (g >= 0) unsafeAtomicAdd(&out[g], t);
    }
}

extern "C" void kernel_launch(void* const* d_in, const int* in_sizes, int n_in,
                              void* d_out, int out_size, void* d_ws, size_t ws_size,
                              hipStream_t stream) {
    (void)in_sizes; (void)n_in; (void)ws_size;
    const int*   node_types = (const int*)d_in[0];
    const int*   edge_types = (const int*)d_in[1];
    const int*   src        = (const int*)d_in[2];
    const int*   dst        = (const int*)d_in[3];
    const int*   graph_ids  = (const int*)d_in[4];
    const float* distances  = (const float*)d_in[5];
    const float* node_emb   = (const float*)d_in[7];
    const float* edge_emb   = (const float*)d_in[8];
    const float* Wn1 = (const float*)d_in[9];
    const float* bn1 = (const float*)d_in[10];
    const float* Wn2 = (const float*)d_in[11];
    const float* bn2 = (const float*)d_in[12];
    const float* We1 = (const float*)d_in[13];
    const float* be1 = (const float*)d_in[14];
    const float* We2 = (const float*)d_in[15];
    const float* be2 = (const float*)d_in[16];
    const float* Wc  = (const float*)d_in[17];
    const float* bc  = (const float*)d_in[18];
    const float* Wr1 = (const float*)d_in[19];
    const float* br1 = (const float*)d_in[20];
    const float* Wr2 = (const float*)d_in[21];
    const float* br2 = (const float*)d_in[22];

    char* w = (char*)d_ws;
    auto carve = [&](size_t bytes) { char* p = w; w += (bytes + 255) & ~(size_t)255; return p; };
    float* h        = (float*)carve((size_t)NNODES * 128 * 4);
    f16*   P        = (f16*)  carve((size_t)NNODES * 128 * 2);
    f16*   T        = (f16*)  carve((size_t)500 * 128 * 2);
    int*   rowStart = (int*)  carve((size_t)(NNODES + 1) * 4);
    int*   cnt      = (int*)  carve((size_t)NNODES * 4);
    int*   blockSum = (int*)  carve((size_t)64 * 4);
    uint4* packE    = (uint4*)carve((size_t)NEDGES * 16);

    float* out = (float*)d_out;
    const int NB1 = (NNODES + 1023) / 1024;   // 49

    init_k<<<(NNODES + 255) / 256, 256, 0, stream>>>(out, out_size, cnt);
    hist_k<<<NEDGES / 256, 256, 0, stream>>>(dst, cnt);
    scan1_k<<<NB1, 1024, 0, stream>>>(cnt, rowStart, blockSum);
    scan2_k<<<1, 64, 0, stream>>>(blockSum, NB1);
    scan3_k<<<NB1, 1024, 0, stream>>>(rowStart, blockSum, cnt);
    scatter_k<<<NEDGES / 256, 256, 0, stream>>>(src, edge_types, dst, distances,
                                                rowStart, cnt, packE);
    gather_h<<<(NNODES * 32 + 255) / 256, 256, 0, stream>>>(node_types, node_emb, h);

    for (int i = 0; i < 3; ++i) {
        mlp_kernel<2><<<(500 + 255) / 256, 1024, 0, stream>>>(
            edge_emb, 500, We1 + (size_t)i * 158 * 128, be1 + i * 128, nullptr, nullptr, T);
        mlp_kernel<0><<<(NNODES + 255) / 256, 1024, 0, stream>>>(
            h, NNODES, Wn1 + (size_t)i * 128 * 128, bn1 + i * 128,
            Wn2 + (size_t)i * 128 * 128, bn2 + i * 128, P);
        edge_kernel<<<256, 1024, 0, stream>>>(
            packE, P, T,
            We1 + (size_t)i * 158 * 128,
            We2 + (size_t)i * 128 * 128, be2 + i * 128,
            Wc + (size_t)i * 128 * 128, bc + i * 128, h);
    }

    readout_k<<<(NNODES + 255) / 256, 1024, 0, stream>>>(
        h, NNODES, Wr1, br1, Wr2, br2, graph_ids, out);
}

// Round 15
// 676.076 us; speedup vs baseline: 1.1719x; 1.0663x over previous
//
#include <hip/hip_runtime.h>
#include <stdint.h>

#define NNODES 50000
#define NEDGES 800000
#define NGRAPH 100
#define NCHUNK (NEDGES / 16)   // 50000 16-edge chunks
#define NWAVES 4096            // 256 blocks x 16 waves
#define NB0 196                // mlp blocks for 50000 rows (256/block)

typedef _Float16 f16;
typedef __attribute__((ext_vector_type(8))) _Float16 half8;
typedef __attribute__((ext_vector_type(4))) _Float16 half4;
typedef __attribute__((ext_vector_type(4))) float floatx4;

// stage 128x128 fp32 row-major W[k][n] -> LDS WT[n][136 pad] fp16, float4 loads
__device__ __forceinline__ void stage_WT(const float* __restrict__ W, f16* WT,
                                         int tid, int nthr) {
    for (int idx = tid; idx < 128 * 32; idx += nthr) {
        int k = idx >> 5, n4 = (idx & 31) * 4;
        floatx4 v = *(const floatx4*)(W + k * 128 + n4);
        WT[(n4 + 0) * 136 + k] = (f16)v[0];
        WT[(n4 + 1) * 136 + k] = (f16)v[1];
        WT[(n4 + 2) * 136 + k] = (f16)v[2];
        WT[(n4 + 3) * 136 + k] = (f16)v[3];
    }
}

__device__ __forceinline__ float fast_tanh(float x) {
    x = fminf(fmaxf(x, -15.0f), 15.0f);
    float e2 = __expf(2.0f * x);
    return (e2 - 1.0f) * __builtin_amdgcn_rcpf(e2 + 1.0f);
}

// transposed-m: column c owns f16 elements [c*16, c*16+16); row groups of 4
// rotated by (c>>2) to spread banks. Bijective per column -> collision-free.
__device__ __forceinline__ int mtAddr(int c, int rgroup) {
    return c * 16 + ((((c >> 2) + rgroup) & 3) << 2);
}

__global__ void init_k(float* out, int osz, int* cnt) {
    int i = blockIdx.x * 256 + threadIdx.x;
    if (i < osz) out[i] = 0.0f;
    if (i < NNODES) cnt[i] = 0;
}

__global__ void hist_k(const int* __restrict__ dst, int* __restrict__ cnt) {
    int e = blockIdx.x * 256 + threadIdx.x;
    if (e < NEDGES) atomicAdd(&cnt[dst[e]], 1);
}

__global__ __launch_bounds__(1024) void scan1_k(const int* __restrict__ cnt,
                                                int* __restrict__ rowStart,
                                                int* __restrict__ blockSum) {
    __shared__ int buf[1024];
    int tid = threadIdx.x;
    int i = blockIdx.x * 1024 + tid;
    int v = (i < NNODES) ? cnt[i] : 0;
    buf[tid] = v;
    __syncthreads();
    for (int off = 1; off < 1024; off <<= 1) {
        int t = (tid >= off) ? buf[tid - off] : 0;
        __syncthreads();
        buf[tid] += t;
        __syncthreads();
    }
    if (i < NNODES) rowStart[i] = buf[tid] - v;
    if (tid == 1023) blockSum[blockIdx.x] = buf[1023];
}

__global__ void scan2_k(int* __restrict__ blockSum, int nb) {
    if (threadIdx.x == 0) {
        int run = 0;
        for (int b = 0; b < nb; ++b) { int s = blockSum[b]; blockSum[b] = run; run += s; }
    }
}

__global__ __launch_bounds__(1024) void scan3_k(int* __restrict__ rowStart,
                                                const int* __restrict__ blockSum,
                                                int* __restrict__ cnt) {
    int i = blockIdx.x * 1024 + threadIdx.x;
    if (i < NNODES) { rowStart[i] += blockSum[blockIdx.x]; cnt[i] = 0; }
    if (i == 0) rowStart[NNODES] = NEDGES;
}

__global__ void scatter_k(const int* __restrict__ src, const int* __restrict__ et,
                          const int* __restrict__ dst, const float* __restrict__ dist,
                          const int* __restrict__ rowStart, int* __restrict__ cnt,
                          uint4* __restrict__ packE) {
    int e = blockIdx.x * 256 + threadIdx.x;
    if (e >= NEDGES) return;
    int d = dst[e];
    int pos = rowStart[d] + atomicAdd(&cnt[d], 1);
    uint4 pk;
    pk.x = (unsigned)src[e];
    pk.y = (unsigned)et[e];
    pk.z = (unsigned)d;
    pk.w = __float_as_uint(dist[e]);
    packE[pos] = pk;
}

__global__ void gather_h(const int* __restrict__ nt, const float* __restrict__ emb,
                         float* __restrict__ h) {
    int i = blockIdx.x * 256 + threadIdx.x;
    int row = i >> 5, c4 = (i & 31) * 4;
    if (row < NNODES)
        *(floatx4*)(h + row * 128 + c4) = *(const floatx4*)(emb + nt[row] * 128 + c4);
}

// ---------------------------------------------------------------------------
// Fused node-MLP + edge-type-table kernel (one launch per layer):
//   blocks [0, NB0)      : P = relu(h@Wn1+bn1)@Wn2+bn2      (50000 rows)
//   blocks [NB0, NB0+2)  : T = edge_emb@We1[:128]+be1        (500 rows)
// Operand-swapped MFMAs -> feature-contiguous C-layout, all LDS b64/b128.
// Mode-2 blocks reuse the same LDS layout (W2T simply unused). The separate
// 2-block mlp<2> launch idled 254 CUs for a full launch cycle, 3x per call.
// ---------------------------------------------------------------------------
__global__ __launch_bounds__(1024, 4) void mlp_combo(
        const float* __restrict__ Xh,
        const float* __restrict__ W1, const float* __restrict__ b1,
        const float* __restrict__ W2, const float* __restrict__ b2,
        f16* __restrict__ OutP,
        const float* __restrict__ Xe,
        const float* __restrict__ We1, const float* __restrict__ be1,
        f16* __restrict__ OutT) {
    __shared__ f16 W1T[128 * 136];
    __shared__ f16 W2T[128 * 136];
    __shared__ f16 xBuf[256 * 136];
    __shared__ float bias1[128];
    __shared__ float bias2[128];
    int tid = threadIdx.x;
    bool mode2 = blockIdx.x >= NB0;

    const float* X  = mode2 ? Xe : Xh;
    const float* Wa = mode2 ? We1 : W1;
    const float* ba = mode2 ? be1 : b1;
    f16* Out        = mode2 ? OutT : OutP;
    int  M          = mode2 ? 500 : NNODES;
    int  r0         = (mode2 ? (blockIdx.x - NB0) : blockIdx.x) * 256;

    stage_WT(Wa, W1T, tid, 1024);
    if (!mode2) stage_WT(W2, W2T, tid, 1024);
    if (tid < 128) { bias1[tid] = ba[tid]; bias2[tid] = mode2 ? 0.0f : b2[tid]; }

    for (int it = 0; it < 8; ++it) {
        int row = it * 32 + (tid >> 5);
        int c4 = (tid & 31) * 4;
        int gr = r0 + row;
        floatx4 x = {0.0f, 0.0f, 0.0f, 0.0f};
        if (gr < M) x = *(const floatx4*)(X + (size_t)gr * 128 + c4);
        half4 xh;
        xh[0] = (f16)x[0]; xh[1] = (f16)x[1]; xh[2] = (f16)x[2]; xh[3] = (f16)x[3];
        *(half4*)(xBuf + row * 136 + c4) = xh;
    }
    __syncthreads();

    int lane = tid & 63, wv = tid >> 6;
    int R = wv * 16;
    int n16 = lane & 15, q = lane >> 4;
    int gr = r0 + R + n16;

    half8 a[4];
    #pragma unroll
    for (int kk = 0; kk < 4; ++kk)
        a[kk] = *(const half8*)(xBuf + (R + n16) * 136 + kk * 32 + q * 8);

    #pragma unroll
    for (int f = 0; f < 8; ++f) {
        floatx4 acc = *(const floatx4*)(bias1 + f * 16 + q * 4);
        #pragma unroll
        for (int kk = 0; kk < 4; ++kk) {
            half8 aw = *(const half8*)(W1T + (f * 16 + n16) * 136 + kk * 32 + q * 8);
            acc = __builtin_amdgcn_mfma_f32_16x16x32_f16(aw, a[kk], acc, 0, 0, 0);
        }
        if (!mode2) {
            half4 y;
            #pragma unroll
            for (int i = 0; i < 4; ++i) y[i] = (f16)fmaxf(acc[i], 0.0f);
            *(half4*)(xBuf + (R + n16) * 136 + f * 16 + q * 4) = y;
        } else {
            half4 o;
            #pragma unroll
            for (int i = 0; i < 4; ++i) o[i] = (f16)acc[i];
            if (gr < M) *(half4*)(Out + (size_t)gr * 128 + f * 16 + q * 4) = o;
        }
    }

    if (!mode2) {
        #pragma unroll
        for (int kk = 0; kk < 4; ++kk)
            a[kk] = *(const half8*)(xBuf + (R + n16) * 136 + kk * 32 + q * 8);
        #pragma unroll
        for (int f = 0; f < 8; ++f) {
            floatx4 acc = *(const floatx4*)(bias2 + f * 16 + q * 4);
            #pragma unroll
            for (int kk = 0; kk < 4; ++kk) {
                half8 aw = *(const half8*)(W2T + (f * 16 + n16) * 136 + kk * 32 + q * 8);
                acc = __builtin_amdgcn_mfma_f32_16x16x32_f16(aw, a[kk], acc, 0, 0, 0);
            }
            half4 o;
            #pragma unroll
            for (int i = 0; i < 4; ++i) o[i] = (f16)acc[i];
            if (gr < M) *(half4*)(Out + (size_t)gr * 128 + f * 16 + q * 4) = o;
        }
    }
}

// ---------------------------------------------------------------------------
// Barrier-free edge kernel (R11 — session optimum, byte-identical). 16
// waves/block, 1 block/CU, wave-local 16-edge chunks, all LDS ops b64/b128
// (operand-swapped MFMAs). MEMORY SCHEDULE ENFORCED WITH sched_barrier(0):
// the compiler otherwise pipelines next-chunk T/P gathers across iterations
// (R8/R10: FETCH 223/226 MB), thrashing the 4 MB per-XCD L2. Fenced:
// FETCH 80.6 MB, WRITE 26.9 MB, 142 us/layer. Pair/tile variants
// (R9/R12/R13) all spilled or thrashed — measured local optimum.
// ---------------------------------------------------------------------------
__global__ __launch_bounds__(1024, 4) void edge_kernel(
        const uint4* __restrict__ packE,
        const f16* __restrict__ P, const f16* __restrict__ T,
        const float* __restrict__ We1,
        const float* __restrict__ We2, const float* __restrict__ be2,
        const float* __restrict__ Wc,  const float* __restrict__ bc,
        float* __restrict__ h) {
    __shared__ f16 W2T[128 * 136];       // 34816 B
    __shared__ f16 WcT[128 * 136];       // 34816 B
    __shared__ f16 W1rT[128 * 40];       // 10240 B
    __shared__ f16 Uall[16 * 2176];      // 69632 B : per-wave 16x136 (T/u/ep) then mT
    __shared__ float sbe2[128], sbc[128];
    __shared__ int dstW[16][16];
    // total ~151.5 KB -> 1 block/CU, 16 waves

    int tid = threadIdx.x;
    stage_WT(We2, W2T, tid, 1024);
    stage_WT(Wc,  WcT, tid, 1024);
    for (int idx = tid; idx < 128 * 32; idx += 1024) {
        int n = idx >> 5, kr = idx & 31;
        W1rT[n * 40 + kr] = (kr < 30) ? (f16)We1[(128 + kr) * 128 + n] : (f16)0.0f;
    }
    if (tid < 128) { sbe2[tid] = be2[tid]; sbc[tid] = bc[tid]; }
    __syncthreads();    // weights ready; the ONLY block barrier

    int lane = tid & 63, wv = tid >> 6;
    f16* U = Uall + wv * 2176;
    int* dW = dstW[wv];
    int n16 = lane & 15, q = lane >> 4;
    const float invgap = 29.0f / 10.0f;
    int colA = lane, colB = lane + 64;
    int tsub = lane & 3, trow = lane >> 2;

    float sbcv[8];
    #pragma unroll
    for (int f = 0; f < 8; ++f) sbcv[f] = sbc[f * 16 + n16];

    // balanced stripe partition: 50000 chunks over 4096 waves (12 or 13 each)
    int wgid = blockIdx.x * 16 + wv;
    int extra = wgid < 848 ? wgid : 848;
    int c0 = wgid * 12 + extra;
    int c1 = c0 + 12 + (wgid < 848 ? 1 : 0);

    float carry0 = 0.0f, carry1 = 0.0f;
    int prev = -1;

    // prologue: pk for chunk c0
    uint4 pk = {0u, 0u, 0u, 0u};
    if (lane < 16) pk = packE[(size_t)c0 * 16 + lane];

    for (int ch = c0; ch < c1; ++ch) {
        bool hasNext = (ch + 1 < c1);
        // ---- distribute current records -----------------------------------
        int   ety  = __shfl((int)pk.y, trow);
        int   srcv = __shfl((int)pk.x, n16);
        float dcur = __shfl(__uint_as_float(pk.w), n16);
        if (lane < 16) dW[lane] = (int)pk.z;

        // ---- T loads, drained into LDS (phase A) --------------------------
        {
            const uint4* Tp = (const uint4*)(T + (size_t)ety * 128 + tsub * 32);
            uint4 tr0 = Tp[0], tr1 = Tp[1], tr2 = Tp[2], tr3 = Tp[3];
            uint4* ub = (uint4*)(U + trow * 136 + tsub * 32);
            ub[0] = tr0; ub[1] = tr1; ub[2] = tr2; ub[3] = tr3;
        }
        __builtin_amdgcn_sched_barrier(0);   // T drained before P issues

        // ---- NOW issue P loads (T no longer in flight) --------------------
        half8 pA0, pA1, pA2, pA3;
        {
            const f16* Pr = P + (size_t)srcv * 128 + q * 8;
            pA0 = *(const half8*)(Pr);
            pA1 = *(const half8*)(Pr + 32);
            pA2 = *(const half8*)(Pr + 64);
            pA3 = *(const half8*)(Pr + 96);
        }
        uint4 pkn = {0u, 0u, 0u, 0u};
        if (hasNext && lane < 16) pkn = packE[(size_t)(ch + 1) * 16 + lane];

        // ---- rbf in regs (VALU overlaps P latency) ------------------------
        half8 ar;
        #pragma unroll
        for (int j = 0; j < 8; ++j) {
            int k = q * 8 + j;
            float c = (float)k * (10.0f / 29.0f);
            float df = dcur - c;
            ar[j] = (f16)((k < 30) ? __expf(-df * df * invgap) : 0.0f);
        }

        // ---- B: u^T = relu(W1r^T @ rbf^T + T^T)  (all b64/b128) -----------
        #pragma unroll
        for (int f = 0; f < 8; ++f) {
            f16* up = U + n16 * 136 + f * 16 + q * 4;
            half4 tv = *(const half4*)up;
            floatx4 c4 = {(float)tv[0], (float)tv[1], (float)tv[2], (float)tv[3]};
            half8 aw = *(const half8*)(W1rT + (f * 16 + n16) * 40 + q * 8);
            c4 = __builtin_amdgcn_mfma_f32_16x16x32_f16(aw, ar, c4, 0, 0, 0);
            half4 uv;
            #pragma unroll
            for (int i = 0; i < 4; ++i) uv[i] = (f16)fmaxf(c4[i], 0.0f);
            *(half4*)up = uv;
        }

        // ---- C: ep^T = W2^T @ u^T + be2 -----------------------------------
        half8 a2[4];
        #pragma unroll
        for (int kk = 0; kk < 4; ++kk)
            a2[kk] = *(const half8*)(U + n16 * 136 + kk * 32 + q * 8);
        #pragma unroll
        for (int f = 0; f < 8; ++f) {
            floatx4 acc = *(const floatx4*)(sbe2 + f * 16 + q * 4);
            #pragma unroll
            for (int kk = 0; kk < 4; ++kk) {
                half8 aw = *(const half8*)(W2T + (f * 16 + n16) * 136 + kk * 32 + q * 8);
                acc = __builtin_amdgcn_mfma_f32_16x16x32_f16(aw, a2[kk], acc, 0, 0, 0);
            }
            half4 ev;
            #pragma unroll
            for (int i = 0; i < 4; ++i) ev[i] = (f16)acc[i];
            *(half4*)(U + n16 * 136 + f * 16 + q * 4) = ev;
        }

        // ---- E: m = tanh((P ⊙ ep) @ Wc + bc); write mT (b64, swizzled) ----
        {
            half8 e0 = *(const half8*)(U + n16 * 136 + 0 * 32 + q * 8);
            half8 e1 = *(const half8*)(U + n16 * 136 + 1 * 32 + q * 8);
            half8 e2 = *(const half8*)(U + n16 * 136 + 2 * 32 + q * 8);
            half8 e3 = *(const half8*)(U + n16 * 136 + 3 * 32 + q * 8);
            a2[0] = e0 * pA0; a2[1] = e1 * pA1; a2[2] = e2 * pA2; a2[3] = e3 * pA3;
        }
        #pragma unroll
        for (int f = 0; f < 8; ++f) {
            float bb = sbcv[f];
            floatx4 acc = {bb, bb, bb, bb};
            #pragma unroll
            for (int kk = 0; kk < 4; ++kk) {
                half8 b = *(const half8*)(WcT + (f * 16 + n16) * 136 + kk * 32 + q * 8);
                acc = __builtin_amdgcn_mfma_f32_16x16x32_f16(a2[kk], b, acc, 0, 0, 0);
            }
            int c = f * 16 + n16;
            half4 mv;
            #pragma unroll
            for (int i = 0; i < 4; ++i) mv[i] = (f16)fast_tanh(acc[i]);
            *(half4*)(U + mtAddr(c, q)) = mv;
        }

        // ---- F: per-col segment reduce with cross-chunk carry -------------
        {
            half4 va[4], vb[4];
            #pragma unroll
            for (int g2 = 0; g2 < 4; ++g2) {
                va[g2] = *(const half4*)(U + mtAddr(colA, g2));
                vb[g2] = *(const half4*)(U + mtAddr(colB, g2));
            }
            int dArr[16];
            *(int4*)(dArr)      = *(const int4*)(dW);
            *(int4*)(dArr + 4)  = *(const int4*)(dW + 4);
            *(int4*)(dArr + 8)  = *(const int4*)(dW + 8);
            *(int4*)(dArr + 12) = *(const int4*)(dW + 12);
            #pragma unroll
            for (int r = 0; r < 16; ++r) {
                int dd = dArr[r];
                float v0 = (float)va[r >> 2][r & 3];
                float v1 = (float)vb[r >> 2][r & 3];
                if (dd != prev) {   // wave-uniform branch
                    if (prev >= 0) {
                        unsafeAtomicAdd(&h[(size_t)prev * 128 + colA], carry0);
                        unsafeAtomicAdd(&h[(size_t)prev * 128 + colB], carry1);
                    }
                    prev = dd; carry0 = v0; carry1 = v1;
                } else { carry0 += v0; carry1 += v1; }
            }
        }
        pk = pkn;
        __builtin_amdgcn_sched_barrier(0);   // no cross-iteration load hoisting
    }
    if (prev >= 0) {
        unsafeAtomicAdd(&h[(size_t)prev * 128 + colA], carry0);
        unsafeAtomicAdd(&h[(size_t)prev * 128 + colB], carry1);
    }
}

// fused readout: hr = relu(h@Wr1+br1)·Wr2 + br2, out[gid] += hr  (per row)
__global__ __launch_bounds__(1024, 4) void readout_k(
        const float* __restrict__ X, int M,
        const float* __restrict__ W1, const float* __restrict__ b1,
        const float* __restrict__ Wr2, const float* __restrict__ br2,
        const int* __restrict__ gid, float* __restrict__ out) {
    __shared__ f16 W1T[128 * 136];
    __shared__ f16 xBuf[256 * 136];
    __shared__ float bias1[128];
    __shared__ float sWr2[128];
    int tid = threadIdx.x;

    stage_WT(W1, W1T, tid, 1024);
    if (tid < 128) { bias1[tid] = b1[tid]; sWr2[tid] = Wr2[tid]; }

    int r0 = blockIdx.x * 256;
    for (int it = 0; it < 8; ++it) {
        int row = it * 32 + (tid >> 5);
        int c4 = (tid & 31) * 4;
        int gr = r0 + row;
        floatx4 x = {0.0f, 0.0f, 0.0f, 0.0f};
        if (gr < M) x = *(const floatx4*)(X + (size_t)gr * 128 + c4);
        half4 xh;
        xh[0] = (f16)x[0]; xh[1] = (f16)x[1]; xh[2] = (f16)x[2]; xh[3] = (f16)x[3];
        *(half4*)(xBuf + row * 136 + c4) = xh;
    }
    __syncthreads();

    int lane = tid & 63, wv = tid >> 6;
    int R = wv * 16;
    int n16 = lane & 15, q = lane >> 4;

    half8 a[4];
    #pragma unroll
    for (int kk = 0; kk < 4; ++kk)
        a[kk] = *(const half8*)(xBuf + (R + n16) * 136 + kk * 32 + q * 8);

    floatx4 acc[8];
    #pragma unroll
    for (int f = 0; f < 8; ++f) {
        float bb = bias1[f * 16 + n16];
        acc[f] = (floatx4){bb, bb, bb, bb};
        #pragma unroll
        for (int kk = 0; kk < 4; ++kk) {
            half8 b = *(const half8*)(W1T + (f * 16 + n16) * 136 + kk * 32 + q * 8);
            acc[f] = __builtin_amdgcn_mfma_f32_16x16x32_f16(a[kk], b, acc[f], 0, 0, 0);
        }
    }

    float s[4];
    #pragma unroll
    for (int i = 0; i < 4; ++i) {
        float t = 0.0f;
        #pragma unroll
        for (int f = 0; f < 8; ++f)
            t += fmaxf(acc[f][i], 0.0f) * sWr2[f * 16 + n16];
        #pragma unroll
        for (int m = 1; m < 16; m <<= 1) t += __shfl_xor(t, m);
        s[i] = t;
    }

    if (n16 == 0) {
        float br2v = br2[0];
        float t = 0.0f; int g = -1;
        #pragma unroll
        for (int i = 0; i < 4; ++i) {
            int gr = r0 + R + q * 4 + i;
            if (gr < M) {
                int gi = gid[gr];
                float si = s[i] + br2v;
                if (gi == g) t += si;
                else { if (g >= 0) unsafeAtomicAdd(&out[g], t); g = gi; t = si; }
            }
        }
        if (g >= 0) unsafeAtomicAdd(&out[g], t);
    }
}

extern "C" void kernel_launch(void* const* d_in, const int* in_sizes, int n_in,
                              void* d_out, int out_size, void* d_ws, size_t ws_size,
                              hipStream_t stream) {
    (void)in_sizes; (void)n_in; (void)ws_size;
    const int*   node_types = (const int*)d_in[0];
    const int*   edge_types = (const int*)d_in[1];
    const int*   src        = (const int*)d_in[2];
    const int*   dst        = (const int*)d_in[3];
    const int*   graph_ids  = (const int*)d_in[4];
    const float* distances  = (const float*)d_in[5];
    const float* node_emb   = (const float*)d_in[7];
    const float* edge_emb   = (const float*)d_in[8];
    const float* Wn1 = (const float*)d_in[9];
    const float* bn1 = (const float*)d_in[10];
    const float* Wn2 = (const float*)d_in[11];
    const float* bn2 = (const float*)d_in[12];
    const float* We1 = (const float*)d_in[13];
    const float* be1 = (const float*)d_in[14];
    const float* We2 = (const float*)d_in[15];
    const float* be2 = (const float*)d_in[16];
    const float* Wc  = (const float*)d_in[17];
    const float* bc  = (const float*)d_in[18];
    const float* Wr1 = (const float*)d_in[19];
    const float* br1 = (const float*)d_in[20];
    const float* Wr2 = (const float*)d_in[21];
    const float* br2 = (const float*)d_in[22];

    char* w = (char*)d_ws;
    auto carve = [&](size_t bytes) { char* p = w; w += (bytes + 255) & ~(size_t)255; return p; };
    float* h        = (float*)carve((size_t)NNODES * 128 * 4);
    f16*   P        = (f16*)  carve((size_t)NNODES * 128 * 2);
    f16*   T        = (f16*)  carve((size_t)500 * 128 * 2);
    int*   rowStart = (int*)  carve((size_t)(NNODES + 1) * 4);
    int*   cnt      = (int*)  carve((size_t)NNODES * 4);
    int*   blockSum = (int*)  carve((size_t)64 * 4);
    uint4* packE    = (uint4*)carve((size_t)NEDGES * 16);

    float* out = (float*)d_out;
    const int NB1 = (NNODES + 1023) / 1024;   // 49

    init_k<<<(NNODES + 255) / 256, 256, 0, stream>>>(out, out_size, cnt);
    hist_k<<<NEDGES / 256, 256, 0, stream>>>(dst, cnt);
    scan1_k<<<NB1, 1024, 0, stream>>>(cnt, rowStart, blockSum);
    scan2_k<<<1, 64, 0, stream>>>(blockSum, NB1);
    scan3_k<<<NB1, 1024, 0, stream>>>(rowStart, blockSum, cnt);
    scatter_k<<<NEDGES / 256, 256, 0, stream>>>(src, edge_types, dst, distances,
                                                rowStart, cnt, packE);
    gather_h<<<(NNODES * 32 + 255) / 256, 256, 0, stream>>>(node_types, node_emb, h);

    for (int i = 0; i < 3; ++i) {
        mlp_combo<<<NB0 + 2, 1024, 0, stream>>>(
            h, Wn1 + (size_t)i * 128 * 128, bn1 + i * 128,
            Wn2 + (size_t)i * 128 * 128, bn2 + i * 128, P,
            edge_emb, We1 + (size_t)i * 158 * 128, be1 + i * 128, T);
        edge_kernel<<<256, 1024, 0, stream>>>(
            packE, P, T,
            We1 + (size_t)i * 158 * 128,
            We2 + (size_t)i * 128 * 128, be2 + i * 128,
            Wc + (size_t)i * 128 * 128, bc + i * 128, h);
    }

    readout_k<<<(NNODES + 255) / 256, 1024, 0, stream>>>(
        h, NNODES, Wr1, br1, Wr2, br2, graph_ids, out);
}